// Round 3
// baseline (578.142 us; speedup 1.0000x reference)
//
#include <hip/hip_runtime.h>
#include <math.h>

// Problem dims (fixed)
#define BB 32
#define LL 2048
#define DD 512
#define DA_ 512
#define NL_ 512

typedef __bf16 bf16;
typedef __bf16 bf16x8 __attribute__((ext_vector_type(8)));
typedef __bf16 bf16x4 __attribute__((ext_vector_type(4)));
typedef float floatx4 __attribute__((ext_vector_type(4)));

// async global->LDS, 16B per lane; LDS dest is wave-uniform base + lane*16
__device__ __forceinline__ void dma16(const void* g, void* l) {
    __builtin_amdgcn_global_load_lds((__attribute__((address_space(1))) void*)g,
                                     (__attribute__((address_space(3))) void*)l,
                                     16, 0, 0);
}

__device__ __forceinline__ float fast_tanh(float x) {
    const float e = __expf(2.f * x);
    return 1.f - 2.f * __builtin_amdgcn_rcpf(e + 1.f);
}

// ---------------------------------------------------------------------------
// Pure-DMA bf16 MFMA GEMM core: C[128x128] += A[128xK] * B[128xK]^T, BK=32.
// v3: kq-major LDS layout for conflict-free ds_read_b128.
//   LDS chunk (kq, row) lives at bf16 offset (kq*128 + row)*8.  DMA writes
//   are linear in chunk index c = tid + it*256 (HW requirement); the global
//   SOURCE is permuted instead: row = tid&127, kq = (tid>>7) + 2*it.
//   Fragment read addr = (quad*128 + row)*16 -> bank-slot = row&7, so each
//   8-lane issue group covers all 8 16B slots (was 2 -> ~4-way conflict).
// Double-buffered 2-phase prefetch; one barrier per K-step.
// 256 threads = 4 waves; wave (wr,wc) owns a 64x64 quadrant, 4x4 16x16 tiles.
// ---------------------------------------------------------------------------
__device__ __forceinline__ void gemm_core(const bf16* __restrict__ A,
                                          const bf16* __restrict__ B,
                                          int K, int lda, int ldb,
                                          floatx4 acc[4][4])
{
    __shared__ bf16 As[2][128 * 32];   // 8 KB per buffer
    __shared__ bf16 Bs[2][128 * 32];
    const int tid = threadIdx.x;
    const int lane = tid & 63, wv = tid >> 6;
    const int wr = wv >> 1, wc = wv & 1;
    const int lm = lane & 15, quad = lane >> 4;

    // per-thread global source (kq-major chunk mapping)
    const int row = tid & 127, kq0 = tid >> 7;
    const bf16* aP = A + (size_t)row * lda + kq0 * 8;
    const bf16* bP = B + (size_t)row * ldb + kq0 * 8;

    // prologue: stage tile 0 into buffer 0
    dma16(aP,      &As[0][tid * 8]);
    dma16(aP + 16, &As[0][2048 + tid * 8]);
    dma16(bP,      &Bs[0][tid * 8]);
    dma16(bP + 16, &Bs[0][2048 + tid * 8]);
    __syncthreads();   // compiler drains vmcnt(0) before s_barrier

    const int nk = K >> 5;
    for (int t = 0; t < nk; ++t) {
        const int cur = t & 1;
        if (t + 1 < nk) {   // prefetch next K-tile into the other buffer
            const int k0 = (t + 1) << 5;
            dma16(aP + k0,      &As[cur ^ 1][tid * 8]);
            dma16(aP + k0 + 16, &As[cur ^ 1][2048 + tid * 8]);
            dma16(bP + k0,      &Bs[cur ^ 1][tid * 8]);
            dma16(bP + k0 + 16, &Bs[cur ^ 1][2048 + tid * 8]);
        }
        bf16x8 af[4], bfr[4];
        #pragma unroll
        for (int tt = 0; tt < 4; ++tt) {
            af[tt]  = *(const bf16x8*)(&As[cur][(quad * 128 + wr * 64 + tt * 16 + lm) * 8]);
            bfr[tt] = *(const bf16x8*)(&Bs[cur][(quad * 128 + wc * 64 + tt * 16 + lm) * 8]);
        }
        __builtin_amdgcn_s_setprio(1);
        #pragma unroll
        for (int i = 0; i < 4; ++i)
            #pragma unroll
            for (int j = 0; j < 4; ++j)
                acc[i][j] = __builtin_amdgcn_mfma_f32_16x16x32_bf16(af[i], bfr[j], acc[i][j], 0, 0, 0);
        __builtin_amdgcn_s_setprio(0);
        __syncthreads();   // drains this iter's prefetch; next iter reads it
    }
}
// C/D layout (verified m89): col = lane&15, row = quad*4 + reg.

// bijective XCD swizzle: nwg % 8 == 0, chunk = nwg/8; block h runs on XCD h%8,
// so logical work w = (h%8)*chunk + h/8 gives each XCD one contiguous range.
__device__ __forceinline__ int xcd_swz(int bid, int chunk_log2) {
    return ((bid & 7) << chunk_log2) | (bid >> 3);
}

// ---------------------------------------------------------------------------
// K_cvt: fp32 -> bf16, n elements (n % 1024 == 0)
// ---------------------------------------------------------------------------
__global__ __launch_bounds__(256) void k_cvt(const float* __restrict__ src,
                                             bf16* __restrict__ dst, int n)
{
    const int i = (blockIdx.x * 256 + threadIdx.x) * 4;
    if (i < n) {
        const float4 v = *(const float4*)(src + i);
        bf16x4 p = {(bf16)v.x, (bf16)v.y, (bf16)v.z, (bf16)v.w};
        *(bf16x4*)(dst + i) = p;
    }
}

// ---------------------------------------------------------------------------
// K_init_wo: wo[b,n] = b3[n]  (gemm3 atomically accumulates into this)
// ---------------------------------------------------------------------------
__global__ __launch_bounds__(256) void k_init_wo(const float* __restrict__ b3,
                                                 float* __restrict__ wo)
{
    const int i = blockIdx.x * 256 + threadIdx.x;   // BB*NL_ total
    wo[i] = b3[i & (NL_ - 1)];
}

// ---------------------------------------------------------------------------
// K0: xT[b, d, l] = bf16(x[b, l, d])  AND  xb[b, l, d] = bf16(x[b, l, d])
// 64x64 tiles via LDS for the transpose; straight copy done during load.
// ---------------------------------------------------------------------------
__global__ __launch_bounds__(256) void k_transpose(const float* __restrict__ x,
                                                   bf16* __restrict__ xT,
                                                   bf16* __restrict__ xb)
{
    __shared__ float T[64][68];
    const int b = blockIdx.z;
    const int l0 = blockIdx.x * 64, d0 = blockIdx.y * 64;
    const int tid = threadIdx.x;
    const float* xsrc = x + ((size_t)b * LL + l0) * DD + d0;
    bf16* xbdst = xb + ((size_t)b * LL + l0) * DD + d0;
    #pragma unroll
    for (int it = 0; it < 4; ++it) {
        const int c = tid + it * 256;
        const int lr = c >> 4, cc = (c & 15) * 4;
        const float4 v = *(const float4*)(xsrc + (size_t)lr * DD + cc);
        T[lr][cc] = v.x; T[lr][cc + 1] = v.y; T[lr][cc + 2] = v.z; T[lr][cc + 3] = v.w;
        bf16x4 p = {(bf16)v.x, (bf16)v.y, (bf16)v.z, (bf16)v.w};
        *(bf16x4*)(xbdst + (size_t)lr * DD + cc) = p;
    }
    __syncthreads();
    const int dl = tid >> 2, ls = (tid & 3) * 16;
    bf16x8 p0, p1;
    #pragma unroll
    for (int j = 0; j < 8; ++j) p0[j] = (bf16)T[ls + j][dl];
    #pragma unroll
    for (int j = 0; j < 8; ++j) p1[j] = (bf16)T[ls + 8 + j][dl];
    bf16* o = xT + ((size_t)b * DD + d0 + dl) * LL + l0 + ls;
    *(bf16x8*)o = p0;
    *(bf16x8*)(o + 8) = p1;
}

// ---------------------------------------------------------------------------
// K1: wb[m, a] = bf16(tanh(sum_d xb[m,d] * W1b[a,d]))   M=B*L, N=DA, K=D
// 1D grid 2048, XCD-swizzled (chunk=256); w = m_idx*4 + n_idx so the 4
// blocks sharing an xb m-panel are adjacent -> same XCD L2.
// ---------------------------------------------------------------------------
__global__ __launch_bounds__(256) void k_gemm1(const bf16* __restrict__ xb,
                                               const bf16* __restrict__ W1b,
                                               bf16* __restrict__ wb)
{
    const int w = xcd_swz(blockIdx.x, 8);      // nwg=2048, chunk=256
    const int n0 = (w & 3) * 128;
    const size_t m0 = (size_t)(w >> 2) * 128;
    floatx4 acc[4][4];
    #pragma unroll
    for (int i = 0; i < 4; ++i)
        #pragma unroll
        for (int j = 0; j < 4; ++j) { floatx4 z = {0.f, 0.f, 0.f, 0.f}; acc[i][j] = z; }
    gemm_core(xb + m0 * DD, W1b + (size_t)n0 * DD, DD, DD, DD, acc);

    const int tid = threadIdx.x, lane = tid & 63, wv = tid >> 6;
    const int wr = wv >> 1, wc = wv & 1, lm = lane & 15, quad = lane >> 4;
    const size_t row0 = m0 + wr * 64 + quad * 4;
    const int col0 = n0 + wc * 64 + lm;
    #pragma unroll
    for (int i = 0; i < 4; ++i)
        #pragma unroll
        for (int j = 0; j < 4; ++j)
            #pragma unroll
            for (int r = 0; r < 4; ++r)
                wb[(row0 + i * 16 + r) * DA_ + col0 + j * 16] = (bf16)fast_tanh(acc[i][j][r]);
}

// ---------------------------------------------------------------------------
// K2: logitsb[b, n, l] = bf16(sum_a W2b[n,a] * wb[b*L+l, a])
// 1D grid 2048, XCD-swizzled; w = c_idx*4 + m_idx so the 4 blocks sharing a
// wb l-panel are adjacent.
// ---------------------------------------------------------------------------
__global__ __launch_bounds__(256) void k_gemm2(const bf16* __restrict__ wb,
                                               const bf16* __restrict__ W2b,
                                               bf16* __restrict__ logitsb)
{
    const int w = xcd_swz(blockIdx.x, 8);      // nwg=2048, chunk=256
    const int c0 = (w >> 2) * 128;   // global l index (never straddles a batch)
    const int m0 = (w & 3) * 128;    // over NL
    floatx4 acc[4][4];
    #pragma unroll
    for (int i = 0; i < 4; ++i)
        #pragma unroll
        for (int j = 0; j < 4; ++j) { floatx4 z = {0.f, 0.f, 0.f, 0.f}; acc[i][j] = z; }
    gemm_core(W2b + (size_t)m0 * DA_, wb + (size_t)c0 * DA_, DA_, DA_, DA_, acc);

    const int b = c0 >> 11, lloc = c0 & (LL - 1);
    const int tid = threadIdx.x, lane = tid & 63, wv = tid >> 6;
    const int wr = wv >> 1, wc = wv & 1, lm = lane & 15, quad = lane >> 4;
    bf16* base = logitsb + ((size_t)b * NL_ + m0 + wr * 64 + quad * 4) * LL
               + lloc + wc * 64 + lm;
    #pragma unroll
    for (int i = 0; i < 4; ++i)
        #pragma unroll
        for (int j = 0; j < 4; ++j)
            #pragma unroll
            for (int r = 0; r < 4; ++r)
                base[(size_t)(i * 16 + r) * LL + j * 16] = (bf16)acc[i][j][r];
}

// ---------------------------------------------------------------------------
// K3: softmax over contiguous L per (b,n): read bf16 logits,
//     write fp32 att (output) + bf16 attb (for gemm3)
// ---------------------------------------------------------------------------
__global__ __launch_bounds__(256) void k_softmax(const bf16* __restrict__ logitsb,
                                                 float* __restrict__ att,
                                                 bf16* __restrict__ attb)
{
    const int tid = threadIdx.x;
    const bf16* p = logitsb + (size_t)blockIdx.x * LL;
    float* po = att + (size_t)blockIdx.x * LL;
    bf16* pb = attb + (size_t)blockIdx.x * LL;

    const bf16x8 v = *(const bf16x8*)(p + tid * 8);
    float f[8];
    #pragma unroll
    for (int j = 0; j < 8; ++j) f[j] = (float)v[j];

    __shared__ float red[8];
    float m = f[0];
    #pragma unroll
    for (int j = 1; j < 8; ++j) m = fmaxf(m, f[j]);
    #pragma unroll
    for (int off = 32; off; off >>= 1) m = fmaxf(m, __shfl_down(m, off));
    if ((tid & 63) == 0) red[tid >> 6] = m;
    __syncthreads();
    m = fmaxf(fmaxf(red[0], red[1]), fmaxf(red[2], red[3]));

    float s = 0.f;
    #pragma unroll
    for (int j = 0; j < 8; ++j) { f[j] = __expf(f[j] - m); s += f[j]; }
    #pragma unroll
    for (int off = 32; off; off >>= 1) s += __shfl_down(s, off);
    if ((tid & 63) == 0) red[4 + (tid >> 6)] = s;
    __syncthreads();
    s = red[4] + red[5] + red[6] + red[7];

    const float inv = 1.0f / s;
    float4 o0, o1;
    o0.x = f[0] * inv; o0.y = f[1] * inv; o0.z = f[2] * inv; o0.w = f[3] * inv;
    o1.x = f[4] * inv; o1.y = f[5] * inv; o1.z = f[6] * inv; o1.w = f[7] * inv;
    *(float4*)(po + tid * 8) = o0;
    *(float4*)(po + tid * 8 + 4) = o1;
    bf16x8 q = {(bf16)o0.x, (bf16)o0.y, (bf16)o0.z, (bf16)o0.w,
                (bf16)o1.x, (bf16)o1.y, (bf16)o1.z, (bf16)o1.w};
    *(bf16x8*)(pb + tid * 8) = q;
}

// ---------------------------------------------------------------------------
// K4: ctx[b, n, d] = sum_l attb[b,n,l] * xT[b,d,l]
//     + fused wo partials: wo[b,n] += sum_{d in tile} ctx*W3 (atomicAdd fp32)
// 1D grid 512, XCD-swizzled (chunk=64): each XCD owns 4 whole batches ->
// attb[b]+xT[b] (4 MB) stays L2-resident, fetch ~= read-once.
// ---------------------------------------------------------------------------
__global__ __launch_bounds__(256) void k_gemm3(const bf16* __restrict__ attb,
                                               const bf16* __restrict__ xT,
                                               float* __restrict__ ctx,
                                               const float* __restrict__ W3,
                                               float* __restrict__ wo)
{
    const int w = xcd_swz(blockIdx.x, 6);      // nwg=512, chunk=64
    const int b  = w >> 4;
    const int m0 = ((w >> 2) & 3) * 128;   // over NL
    const int n0 = (w & 3) * 128;          // over D
    floatx4 acc[4][4];
    #pragma unroll
    for (int i = 0; i < 4; ++i)
        #pragma unroll
        for (int j = 0; j < 4; ++j) { floatx4 z = {0.f, 0.f, 0.f, 0.f}; acc[i][j] = z; }
    gemm_core(attb + ((size_t)b * NL_ + m0) * LL,
              xT + ((size_t)b * DD + n0) * LL, LL, LL, LL, acc);

    const int tid = threadIdx.x, lane = tid & 63, wv = tid >> 6;
    const int wr = wv >> 1, wc = wv & 1, lm = lane & 15, quad = lane >> 4;
    float* base = ctx + ((size_t)b * NL_ + m0 + wr * 64 + quad * 4) * DD
                + n0 + wc * 64 + lm;
    #pragma unroll
    for (int i = 0; i < 4; ++i)
        #pragma unroll
        for (int j = 0; j < 4; ++j)
            #pragma unroll
            for (int r = 0; r < 4; ++r)
                base[(size_t)(i * 16 + r) * DD + j * 16] = acc[i][j][r];

    // fused wo: this thread's acc covers n = m0+wr*64+quad*4+i*16+r,
    //                                  d = n0+wc*64+lm+j*16
    const int nbase = m0 + wr * 64 + quad * 4;
    const int dbase = n0 + wc * 64 + lm;
    #pragma unroll
    for (int i = 0; i < 4; ++i) {
        #pragma unroll
        for (int r = 0; r < 4; ++r) {
            const int n = nbase + i * 16 + r;
            float s = 0.f;
            #pragma unroll
            for (int j = 0; j < 4; ++j)
                s += acc[i][j][r] * W3[(size_t)n * DD + dbase + j * 16];
            // reduce across the 16 lm lanes of this quad (lm==0 keeps result)
            #pragma unroll
            for (int off = 8; off; off >>= 1) s += __shfl_down(s, off);
            if (lm == 0) atomicAdd(&wo[(size_t)b * NL_ + n], s);
        }
    }
}

// ---------------------------------------------------------------------------
extern "C" void kernel_launch(void* const* d_in, const int* in_sizes, int n_in,
                              void* d_out, int out_size, void* d_ws, size_t ws_size,
                              hipStream_t stream)
{
    const float* x  = (const float*)d_in[0];
    const float* W1 = (const float*)d_in[1];
    const float* W2 = (const float*)d_in[2];
    const float* W3 = (const float*)d_in[3];
    const float* b3 = (const float*)d_in[4];

    float* out = (float*)d_out;
    float* ctx = out;                               // [B, NL, D]
    float* wo  = out + (size_t)BB * NL_ * DD;       // [B, NL]
    float* att = wo + (size_t)BB * NL_;             // [B, NL, L]

    // ws layout (193 MB):
    //   R0 xT [B,D,L]          64 MB
    //   R1 xb [B*L,D] -> logitsb [B,NL,L]  64 MB (xb dead after gemm1)
    //   R2 wb [B*L,DA] -> attb [B,NL,L]    64 MB (wb dead after gemm2)
    //   R3 W1b, W2b            1 MB
    char* wsp = (char*)d_ws;
    const size_t M64 = (size_t)64 * 1024 * 1024;
    bf16* xT      = (bf16*)(wsp);
    bf16* xb      = (bf16*)(wsp + M64);
    bf16* logitsb = (bf16*)(wsp + M64);
    bf16* wb      = (bf16*)(wsp + 2 * M64);
    bf16* attb    = (bf16*)(wsp + 2 * M64);
    bf16* W1b     = (bf16*)(wsp + 3 * M64);
    bf16* W2b     = W1b + (size_t)DA_ * DD;

    k_cvt<<<(DA_ * DD) / 1024, 256, 0, stream>>>(W1, W1b, DA_ * DD);
    k_cvt<<<(NL_ * DA_) / 1024, 256, 0, stream>>>(W2, W2b, NL_ * DA_);
    k_init_wo<<<(BB * NL_) / 256, 256, 0, stream>>>(b3, wo);
    k_transpose<<<dim3(LL / 64, DD / 64, BB), 256, 0, stream>>>(x, xT, xb);
    k_gemm1<<<2048, 256, 0, stream>>>(xb, W1b, wb);
    k_gemm2<<<2048, 256, 0, stream>>>(wb, W2b, logitsb);
    k_softmax<<<BB * NL_, 256, 0, stream>>>(logitsb, att, attb);
    k_gemm3<<<512, 256, 0, stream>>>(attb, xT, ctx, W3, wo);
}

// Round 4
// 509.047 us; speedup vs baseline: 1.1357x; 1.1357x over previous
//
#include <hip/hip_runtime.h>
#include <math.h>

// Problem dims (fixed)
#define BB 32
#define LL 2048
#define DD 512
#define DA_ 512
#define NL_ 512

typedef __bf16 bf16;
typedef __bf16 bf16x8 __attribute__((ext_vector_type(8)));
typedef __bf16 bf16x4 __attribute__((ext_vector_type(4)));
typedef float floatx4 __attribute__((ext_vector_type(4)));

// async global->LDS, 16B per lane; LDS dest is wave-uniform base + lane*16
__device__ __forceinline__ void dma16(const void* g, void* l) {
    __builtin_amdgcn_global_load_lds((__attribute__((address_space(1))) void*)g,
                                     (__attribute__((address_space(3))) void*)l,
                                     16, 0, 0);
}

__device__ __forceinline__ float fast_tanh(float x) {
    const float e = __expf(2.f * x);
    return 1.f - 2.f * __builtin_amdgcn_rcpf(e + 1.f);
}

// ---------------------------------------------------------------------------
// Pure-DMA bf16 MFMA GEMM core: C[128x128] += A[128xK] * B[128xK]^T, BK=32.
// v4: rotated-kq LDS layout = coalesced global reads AND conflict-free
// ds_read_b128.
//   Chunk c (linear LDS 16B slot, written by lane c&63 of wave c>>6) holds
//   global (row = c>>2, kq = ((c&3) - (row>>3)) & 3)  [16B sub-slice kq of
//   the row's 64B K-slab].  Every 4-lane group still covers one row's 64B
//   contiguously -> 16 cache lines per dma16 (round-0 coalescing; the
//   round-3 kq-major scatter touched 64 lines/instr = 4x transactions).
//   Fragment read addr for (row r, slice q): elem r*32 + ((q+(r>>3))&3)*8;
//   per 16-lane issue phase the rows map to 16 DISTINCT 16B bank-slots
//   (the r>>3 rotation splits r / r+8 which plain row-major aliases ->
//   round-1's 4.19M SQ_LDS_BANK_CONFLICT; round-3 measured this read
//   family conflict-free).
// Double-buffered 2-phase prefetch; one barrier per K-step.
// 256 threads = 4 waves; wave (wr,wc) owns a 64x64 quadrant, 4x4 16x16 tiles.
// ---------------------------------------------------------------------------
__device__ __forceinline__ void gemm_core(const bf16* __restrict__ A,
                                          const bf16* __restrict__ B,
                                          int K, int lda, int ldb,
                                          floatx4 acc[4][4])
{
    __shared__ bf16 As[2][128 * 32];   // 8 KB per buffer
    __shared__ bf16 Bs[2][128 * 32];
    const int tid = threadIdx.x;
    const int lane = tid & 63, wv = tid >> 6;
    const int wr = wv >> 1, wc = wv & 1;
    const int lm = lane & 15, quad = lane >> 4;

    // staging source: chunk c=tid -> row=tid>>2 (0..63), rotated kq.
    // chunk c=tid+256 -> row+64, SAME kq ((row+64)>>3 == row>>3 mod 4).
    const int srow = tid >> 2;
    const int kq = ((tid & 3) - (srow >> 3)) & 3;
    const bf16* aP = A + (size_t)srow * lda + kq * 8;
    const bf16* bP = B + (size_t)srow * ldb + kq * 8;
    const size_t a1 = (size_t)64 * lda, b1 = (size_t)64 * ldb;

    // prologue: stage tile 0 into buffer 0
    dma16(aP,      &As[0][tid * 8]);
    dma16(aP + a1, &As[0][2048 + tid * 8]);
    dma16(bP,      &Bs[0][tid * 8]);
    dma16(bP + b1, &Bs[0][2048 + tid * 8]);
    __syncthreads();   // compiler drains vmcnt(0) before s_barrier

    const int nk = K >> 5;
    for (int t = 0; t < nk; ++t) {
        const int cur = t & 1;
        if (t + 1 < nk) {   // prefetch next K-tile into the other buffer
            const int k0 = (t + 1) << 5;
            dma16(aP + k0,      &As[cur ^ 1][tid * 8]);
            dma16(aP + a1 + k0, &As[cur ^ 1][2048 + tid * 8]);
            dma16(bP + k0,      &Bs[cur ^ 1][tid * 8]);
            dma16(bP + b1 + k0, &Bs[cur ^ 1][2048 + tid * 8]);
        }
        bf16x8 af[4], bfr[4];
        #pragma unroll
        for (int tt = 0; tt < 4; ++tt) {
            const int rA = wr * 64 + tt * 16 + lm;
            af[tt]  = *(const bf16x8*)(&As[cur][rA * 32 + (((quad + (rA >> 3)) & 3) * 8)]);
            const int rB = wc * 64 + tt * 16 + lm;
            bfr[tt] = *(const bf16x8*)(&Bs[cur][rB * 32 + (((quad + (rB >> 3)) & 3) * 8)]);
        }
        __builtin_amdgcn_s_setprio(1);
        #pragma unroll
        for (int i = 0; i < 4; ++i)
            #pragma unroll
            for (int j = 0; j < 4; ++j)
                acc[i][j] = __builtin_amdgcn_mfma_f32_16x16x32_bf16(af[i], bfr[j], acc[i][j], 0, 0, 0);
        __builtin_amdgcn_s_setprio(0);
        __syncthreads();   // drains this iter's prefetch; next iter reads it
    }
}
// C/D layout (verified m89): col = lane&15, row = quad*4 + reg.

// bijective XCD swizzle: nwg % 8 == 0, chunk = nwg/8; block h runs on XCD h%8,
// so logical work w = (h%8)*chunk + h/8 gives each XCD one contiguous range.
__device__ __forceinline__ int xcd_swz(int bid, int chunk_log2) {
    return ((bid & 7) << chunk_log2) | (bid >> 3);
}

// ---------------------------------------------------------------------------
// K_cvt: fp32 -> bf16, n elements (n % 1024 == 0)
// ---------------------------------------------------------------------------
__global__ __launch_bounds__(256) void k_cvt(const float* __restrict__ src,
                                             bf16* __restrict__ dst, int n)
{
    const int i = (blockIdx.x * 256 + threadIdx.x) * 4;
    if (i < n) {
        const float4 v = *(const float4*)(src + i);
        bf16x4 p = {(bf16)v.x, (bf16)v.y, (bf16)v.z, (bf16)v.w};
        *(bf16x4*)(dst + i) = p;
    }
}

// ---------------------------------------------------------------------------
// K_init_wo: wo[b,n] = b3[n]  (gemm3 atomically accumulates into this)
// ---------------------------------------------------------------------------
__global__ __launch_bounds__(256) void k_init_wo(const float* __restrict__ b3,
                                                 float* __restrict__ wo)
{
    const int i = blockIdx.x * 256 + threadIdx.x;   // BB*NL_ total
    wo[i] = b3[i & (NL_ - 1)];
}

// ---------------------------------------------------------------------------
// K0: xT[b, d, l] = bf16(x[b, l, d])  AND  xb[b, l, d] = bf16(x[b, l, d])
// 64x64 tiles via LDS for the transpose; straight copy done during load.
// ---------------------------------------------------------------------------
__global__ __launch_bounds__(256) void k_transpose(const float* __restrict__ x,
                                                   bf16* __restrict__ xT,
                                                   bf16* __restrict__ xb)
{
    __shared__ float T[64][68];
    const int b = blockIdx.z;
    const int l0 = blockIdx.x * 64, d0 = blockIdx.y * 64;
    const int tid = threadIdx.x;
    const float* xsrc = x + ((size_t)b * LL + l0) * DD + d0;
    bf16* xbdst = xb + ((size_t)b * LL + l0) * DD + d0;
    #pragma unroll
    for (int it = 0; it < 4; ++it) {
        const int c = tid + it * 256;
        const int lr = c >> 4, cc = (c & 15) * 4;
        const float4 v = *(const float4*)(xsrc + (size_t)lr * DD + cc);
        T[lr][cc] = v.x; T[lr][cc + 1] = v.y; T[lr][cc + 2] = v.z; T[lr][cc + 3] = v.w;
        bf16x4 p = {(bf16)v.x, (bf16)v.y, (bf16)v.z, (bf16)v.w};
        *(bf16x4*)(xbdst + (size_t)lr * DD + cc) = p;
    }
    __syncthreads();
    const int dl = tid >> 2, ls = (tid & 3) * 16;
    bf16x8 p0, p1;
    #pragma unroll
    for (int j = 0; j < 8; ++j) p0[j] = (bf16)T[ls + j][dl];
    #pragma unroll
    for (int j = 0; j < 8; ++j) p1[j] = (bf16)T[ls + 8 + j][dl];
    bf16* o = xT + ((size_t)b * DD + d0 + dl) * LL + l0 + ls;
    *(bf16x8*)o = p0;
    *(bf16x8*)(o + 8) = p1;
}

// ---------------------------------------------------------------------------
// K1: wb[m, a] = bf16(tanh(sum_d xb[m,d] * W1b[a,d]))   M=B*L, N=DA, K=D
// 1D grid 2048, XCD-swizzled (chunk=256); w = m_idx*4 + n_idx so the 4
// blocks sharing an xb m-panel are adjacent -> same XCD L2.
// ---------------------------------------------------------------------------
__global__ __launch_bounds__(256) void k_gemm1(const bf16* __restrict__ xb,
                                               const bf16* __restrict__ W1b,
                                               bf16* __restrict__ wb)
{
    const int w = xcd_swz(blockIdx.x, 8);      // nwg=2048, chunk=256
    const int n0 = (w & 3) * 128;
    const size_t m0 = (size_t)(w >> 2) * 128;
    floatx4 acc[4][4];
    #pragma unroll
    for (int i = 0; i < 4; ++i)
        #pragma unroll
        for (int j = 0; j < 4; ++j) { floatx4 z = {0.f, 0.f, 0.f, 0.f}; acc[i][j] = z; }
    gemm_core(xb + m0 * DD, W1b + (size_t)n0 * DD, DD, DD, DD, acc);

    const int tid = threadIdx.x, lane = tid & 63, wv = tid >> 6;
    const int wr = wv >> 1, wc = wv & 1, lm = lane & 15, quad = lane >> 4;
    const size_t row0 = m0 + wr * 64 + quad * 4;
    const int col0 = n0 + wc * 64 + lm;
    #pragma unroll
    for (int i = 0; i < 4; ++i)
        #pragma unroll
        for (int j = 0; j < 4; ++j)
            #pragma unroll
            for (int r = 0; r < 4; ++r)
                wb[(row0 + i * 16 + r) * DA_ + col0 + j * 16] = (bf16)fast_tanh(acc[i][j][r]);
}

// ---------------------------------------------------------------------------
// K2: logitsb[b, n, l] = bf16(sum_a W2b[n,a] * wb[b*L+l, a])
// 1D grid 2048, XCD-swizzled; w = c_idx*4 + m_idx so the 4 blocks sharing a
// wb l-panel are adjacent.
// ---------------------------------------------------------------------------
__global__ __launch_bounds__(256) void k_gemm2(const bf16* __restrict__ wb,
                                               const bf16* __restrict__ W2b,
                                               bf16* __restrict__ logitsb)
{
    const int w = xcd_swz(blockIdx.x, 8);      // nwg=2048, chunk=256
    const int c0 = (w >> 2) * 128;   // global l index (never straddles a batch)
    const int m0 = (w & 3) * 128;    // over NL
    floatx4 acc[4][4];
    #pragma unroll
    for (int i = 0; i < 4; ++i)
        #pragma unroll
        for (int j = 0; j < 4; ++j) { floatx4 z = {0.f, 0.f, 0.f, 0.f}; acc[i][j] = z; }
    gemm_core(W2b + (size_t)m0 * DA_, wb + (size_t)c0 * DA_, DA_, DA_, DA_, acc);

    const int b = c0 >> 11, lloc = c0 & (LL - 1);
    const int tid = threadIdx.x, lane = tid & 63, wv = tid >> 6;
    const int wr = wv >> 1, wc = wv & 1, lm = lane & 15, quad = lane >> 4;
    bf16* base = logitsb + ((size_t)b * NL_ + m0 + wr * 64 + quad * 4) * LL
               + lloc + wc * 64 + lm;
    #pragma unroll
    for (int i = 0; i < 4; ++i)
        #pragma unroll
        for (int j = 0; j < 4; ++j)
            #pragma unroll
            for (int r = 0; r < 4; ++r)
                base[(size_t)(i * 16 + r) * LL + j * 16] = (bf16)acc[i][j][r];
}

// ---------------------------------------------------------------------------
// K3: softmax over contiguous L per (b,n): read bf16 logits,
//     write fp32 att (output) + bf16 attb (for gemm3)
// ---------------------------------------------------------------------------
__global__ __launch_bounds__(256) void k_softmax(const bf16* __restrict__ logitsb,
                                                 float* __restrict__ att,
                                                 bf16* __restrict__ attb)
{
    const int tid = threadIdx.x;
    const bf16* p = logitsb + (size_t)blockIdx.x * LL;
    float* po = att + (size_t)blockIdx.x * LL;
    bf16* pb = attb + (size_t)blockIdx.x * LL;

    const bf16x8 v = *(const bf16x8*)(p + tid * 8);
    float f[8];
    #pragma unroll
    for (int j = 0; j < 8; ++j) f[j] = (float)v[j];

    __shared__ float red[8];
    float m = f[0];
    #pragma unroll
    for (int j = 1; j < 8; ++j) m = fmaxf(m, f[j]);
    #pragma unroll
    for (int off = 32; off; off >>= 1) m = fmaxf(m, __shfl_down(m, off));
    if ((tid & 63) == 0) red[tid >> 6] = m;
    __syncthreads();
    m = fmaxf(fmaxf(red[0], red[1]), fmaxf(red[2], red[3]));

    float s = 0.f;
    #pragma unroll
    for (int j = 0; j < 8; ++j) { f[j] = __expf(f[j] - m); s += f[j]; }
    #pragma unroll
    for (int off = 32; off; off >>= 1) s += __shfl_down(s, off);
    if ((tid & 63) == 0) red[4 + (tid >> 6)] = s;
    __syncthreads();
    s = red[4] + red[5] + red[6] + red[7];

    const float inv = 1.0f / s;
    float4 o0, o1;
    o0.x = f[0] * inv; o0.y = f[1] * inv; o0.z = f[2] * inv; o0.w = f[3] * inv;
    o1.x = f[4] * inv; o1.y = f[5] * inv; o1.z = f[6] * inv; o1.w = f[7] * inv;
    *(float4*)(po + tid * 8) = o0;
    *(float4*)(po + tid * 8 + 4) = o1;
    bf16x8 q = {(bf16)o0.x, (bf16)o0.y, (bf16)o0.z, (bf16)o0.w,
                (bf16)o1.x, (bf16)o1.y, (bf16)o1.z, (bf16)o1.w};
    *(bf16x8*)(pb + tid * 8) = q;
}

// ---------------------------------------------------------------------------
// K4: ctx[b, n, d] = sum_l attb[b,n,l] * xT[b,d,l]
//     + fused wo partials: wo[b,n] += sum_{d in tile} ctx*W3 (atomicAdd fp32)
// 1D grid 512, XCD-swizzled (chunk=64): each XCD owns 4 whole batches ->
// attb[b]+xT[b] (4 MB) stays L2-resident, fetch ~= read-once.
// ---------------------------------------------------------------------------
__global__ __launch_bounds__(256) void k_gemm3(const bf16* __restrict__ attb,
                                               const bf16* __restrict__ xT,
                                               float* __restrict__ ctx,
                                               const float* __restrict__ W3,
                                               float* __restrict__ wo)
{
    const int w = xcd_swz(blockIdx.x, 6);      // nwg=512, chunk=64
    const int b  = w >> 4;
    const int m0 = ((w >> 2) & 3) * 128;   // over NL
    const int n0 = (w & 3) * 128;          // over D
    floatx4 acc[4][4];
    #pragma unroll
    for (int i = 0; i < 4; ++i)
        #pragma unroll
        for (int j = 0; j < 4; ++j) { floatx4 z = {0.f, 0.f, 0.f, 0.f}; acc[i][j] = z; }
    gemm_core(attb + ((size_t)b * NL_ + m0) * LL,
              xT + ((size_t)b * DD + n0) * LL, LL, LL, LL, acc);

    const int tid = threadIdx.x, lane = tid & 63, wv = tid >> 6;
    const int wr = wv >> 1, wc = wv & 1, lm = lane & 15, quad = lane >> 4;
    float* base = ctx + ((size_t)b * NL_ + m0 + wr * 64 + quad * 4) * DD
                + n0 + wc * 64 + lm;
    #pragma unroll
    for (int i = 0; i < 4; ++i)
        #pragma unroll
        for (int j = 0; j < 4; ++j)
            #pragma unroll
            for (int r = 0; r < 4; ++r)
                base[(size_t)(i * 16 + r) * DD + j * 16] = acc[i][j][r];

    // fused wo: this thread's acc covers n = m0+wr*64+quad*4+i*16+r,
    //                                  d = n0+wc*64+lm+j*16
    const int nbase = m0 + wr * 64 + quad * 4;
    const int dbase = n0 + wc * 64 + lm;
    #pragma unroll
    for (int i = 0; i < 4; ++i) {
        #pragma unroll
        for (int r = 0; r < 4; ++r) {
            const int n = nbase + i * 16 + r;
            float s = 0.f;
            #pragma unroll
            for (int j = 0; j < 4; ++j)
                s += acc[i][j][r] * W3[(size_t)n * DD + dbase + j * 16];
            // reduce across the 16 lm lanes of this quad (lm==0 keeps result)
            #pragma unroll
            for (int off = 8; off; off >>= 1) s += __shfl_down(s, off);
            if (lm == 0) atomicAdd(&wo[(size_t)b * NL_ + n], s);
        }
    }
}

// ---------------------------------------------------------------------------
extern "C" void kernel_launch(void* const* d_in, const int* in_sizes, int n_in,
                              void* d_out, int out_size, void* d_ws, size_t ws_size,
                              hipStream_t stream)
{
    const float* x  = (const float*)d_in[0];
    const float* W1 = (const float*)d_in[1];
    const float* W2 = (const float*)d_in[2];
    const float* W3 = (const float*)d_in[3];
    const float* b3 = (const float*)d_in[4];

    float* out = (float*)d_out;
    float* ctx = out;                               // [B, NL, D]
    float* wo  = out + (size_t)BB * NL_ * DD;       // [B, NL]
    float* att = wo + (size_t)BB * NL_;             // [B, NL, L]

    // ws layout (193 MB):
    //   R0 xT [B,D,L]          64 MB
    //   R1 xb [B*L,D] -> logitsb [B,NL,L]  64 MB (xb dead after gemm1)
    //   R2 wb [B*L,DA] -> attb [B,NL,L]    64 MB (wb dead after gemm2)
    //   R3 W1b, W2b            1 MB
    char* wsp = (char*)d_ws;
    const size_t M64 = (size_t)64 * 1024 * 1024;
    bf16* xT      = (bf16*)(wsp);
    bf16* xb      = (bf16*)(wsp + M64);
    bf16* logitsb = (bf16*)(wsp + M64);
    bf16* wb      = (bf16*)(wsp + 2 * M64);
    bf16* attb    = (bf16*)(wsp + 2 * M64);
    bf16* W1b     = (bf16*)(wsp + 3 * M64);
    bf16* W2b     = W1b + (size_t)DA_ * DD;

    k_cvt<<<(DA_ * DD) / 1024, 256, 0, stream>>>(W1, W1b, DA_ * DD);
    k_cvt<<<(NL_ * DA_) / 1024, 256, 0, stream>>>(W2, W2b, NL_ * DA_);
    k_init_wo<<<(BB * NL_) / 256, 256, 0, stream>>>(b3, wo);
    k_transpose<<<dim3(LL / 64, DD / 64, BB), 256, 0, stream>>>(x, xT, xb);
    k_gemm1<<<2048, 256, 0, stream>>>(xb, W1b, wb);
    k_gemm2<<<2048, 256, 0, stream>>>(wb, W2b, logitsb);
    k_softmax<<<BB * NL_, 256, 0, stream>>>(logitsb, att, attb);
    k_gemm3<<<512, 256, 0, stream>>>(attb, xT, ctx, W3, wo);
}

// Round 5
// 507.995 us; speedup vs baseline: 1.1381x; 1.0021x over previous
//
#include <hip/hip_runtime.h>
#include <math.h>

// Problem dims (fixed)
#define BB 32
#define LL 2048
#define DD 512
#define DA_ 512
#define NL_ 512

typedef __bf16 bf16;
typedef __bf16 bf16x8 __attribute__((ext_vector_type(8)));
typedef __bf16 bf16x4 __attribute__((ext_vector_type(4)));
typedef float floatx4 __attribute__((ext_vector_type(4)));

// async global->LDS, 16B per lane; LDS dest is wave-uniform base + lane*16
__device__ __forceinline__ void dma16(const void* g, void* l) {
    __builtin_amdgcn_global_load_lds((__attribute__((address_space(1))) void*)g,
                                     (__attribute__((address_space(3))) void*)l,
                                     16, 0, 0);
}

__device__ __forceinline__ float fast_tanh(float x) {
    const float e = __expf(2.f * x);
    return 1.f - 2.f * __builtin_amdgcn_rcpf(e + 1.f);
}

// ---------------------------------------------------------------------------
// Pure-DMA bf16 MFMA GEMM core: C[128x128] += A[128xK] * B[128xK]^T, BK=32.
// v5: rotation f(r) = (r>>1)&3  — coalesced global reads AND conflict-free
// ds_read_b128 under the 16-lane-phase conflict model fitted to rounds 1/3/4:
//   conflicts are counted among the 16 lanes of a quad; 2 lanes/16B-granule
//   is free (m136).
//   LDS 16B-slot n holds global (row = n>>2, slice = ((n&3)-((n>>3)&3))&3).
//   - staging chunk c: 4-lane groups cover one row's 64B contiguously
//     -> 16 cache lines / dma16 (round-0 coalescing; round-3's kq-major
//     scatter was 64 lines -> 4x transactions, dur 119us).
//   - fragment read (row r, slice q) at slot 4r + ((q+((r>>1)&3))&3):
//     within a quad-phase the granule (slot mod 8) = 4*(r&1) + slot_rot,
//     and (parity, rot) pairs over lm=0..15 hit every granule EXACTLY 2x
//     -> free. (round-1: 8 lanes/granule; round-4's f=r>>3: 4 lanes.)
// Double-buffered 2-phase prefetch; one barrier per K-step.
// 256 threads = 4 waves; wave (wr,wc) owns a 64x64 quadrant, 4x4 16x16 tiles.
// ---------------------------------------------------------------------------
__device__ __forceinline__ void gemm_core(const bf16* __restrict__ A,
                                          const bf16* __restrict__ B,
                                          int K, int lda, int ldb,
                                          floatx4 acc[4][4])
{
    __shared__ bf16 As[2][128 * 32];   // 8 KB per buffer
    __shared__ bf16 Bs[2][128 * 32];
    const int tid = threadIdx.x;
    const int lane = tid & 63, wv = tid >> 6;
    const int wr = wv >> 1, wc = wv & 1;
    const int lm = lane & 15, quad = lane >> 4;

    // staging source: chunk c=tid -> row=tid>>2, slice=((c&3)-((c>>3)&3))&3.
    // chunk c=tid+256 -> row+64, SAME slice ((tid+256)>>3 == tid>>3 mod 4).
    const int srow = tid >> 2;
    const int kq = ((tid & 3) - ((tid >> 3) & 3)) & 3;
    const bf16* aP = A + (size_t)srow * lda + kq * 8;
    const bf16* bP = B + (size_t)srow * ldb + kq * 8;
    const size_t a1 = (size_t)64 * lda, b1 = (size_t)64 * ldb;

    // prologue: stage tile 0 into buffer 0
    dma16(aP,      &As[0][tid * 8]);
    dma16(aP + a1, &As[0][2048 + tid * 8]);
    dma16(bP,      &Bs[0][tid * 8]);
    dma16(bP + b1, &Bs[0][2048 + tid * 8]);
    __syncthreads();   // compiler drains vmcnt(0) before s_barrier

    const int nk = K >> 5;
    for (int t = 0; t < nk; ++t) {
        const int cur = t & 1;
        if (t + 1 < nk) {   // prefetch next K-tile into the other buffer
            const int k0 = (t + 1) << 5;
            dma16(aP + k0,      &As[cur ^ 1][tid * 8]);
            dma16(aP + a1 + k0, &As[cur ^ 1][2048 + tid * 8]);
            dma16(bP + k0,      &Bs[cur ^ 1][tid * 8]);
            dma16(bP + b1 + k0, &Bs[cur ^ 1][2048 + tid * 8]);
        }
        bf16x8 af[4], bfr[4];
        #pragma unroll
        for (int tt = 0; tt < 4; ++tt) {
            const int rA = wr * 64 + tt * 16 + lm;
            af[tt]  = *(const bf16x8*)(&As[cur][rA * 32 + (((quad + ((rA >> 1) & 3)) & 3) * 8)]);
            const int rB = wc * 64 + tt * 16 + lm;
            bfr[tt] = *(const bf16x8*)(&Bs[cur][rB * 32 + (((quad + ((rB >> 1) & 3)) & 3) * 8)]);
        }
        __builtin_amdgcn_s_setprio(1);
        #pragma unroll
        for (int i = 0; i < 4; ++i)
            #pragma unroll
            for (int j = 0; j < 4; ++j)
                acc[i][j] = __builtin_amdgcn_mfma_f32_16x16x32_bf16(af[i], bfr[j], acc[i][j], 0, 0, 0);
        __builtin_amdgcn_s_setprio(0);
        __syncthreads();   // drains this iter's prefetch; next iter reads it
    }
}
// C/D layout (verified m89): col = lane&15, row = quad*4 + reg.

// bijective XCD swizzle: nwg % 8 == 0, chunk = nwg/8; block h runs on XCD h%8,
// so logical work w = (h%8)*chunk + h/8 gives each XCD one contiguous range.
__device__ __forceinline__ int xcd_swz(int bid, int chunk_log2) {
    return ((bid & 7) << chunk_log2) | (bid >> 3);
}

// ---------------------------------------------------------------------------
// K_cvt: fp32 -> bf16, n elements (n % 1024 == 0)
// ---------------------------------------------------------------------------
__global__ __launch_bounds__(256) void k_cvt(const float* __restrict__ src,
                                             bf16* __restrict__ dst, int n)
{
    const int i = (blockIdx.x * 256 + threadIdx.x) * 4;
    if (i < n) {
        const float4 v = *(const float4*)(src + i);
        bf16x4 p = {(bf16)v.x, (bf16)v.y, (bf16)v.z, (bf16)v.w};
        *(bf16x4*)(dst + i) = p;
    }
}

// ---------------------------------------------------------------------------
// K_init_wo: wo[b,n] = b3[n]  (gemm3 atomically accumulates into this)
// ---------------------------------------------------------------------------
__global__ __launch_bounds__(256) void k_init_wo(const float* __restrict__ b3,
                                                 float* __restrict__ wo)
{
    const int i = blockIdx.x * 256 + threadIdx.x;   // BB*NL_ total
    wo[i] = b3[i & (NL_ - 1)];
}

// ---------------------------------------------------------------------------
// K0: xT[b, d, l] = bf16(x[b, l, d])  AND  xb[b, l, d] = bf16(x[b, l, d])
// 64x64 tiles via LDS for the transpose; straight copy done during load.
// ---------------------------------------------------------------------------
__global__ __launch_bounds__(256) void k_transpose(const float* __restrict__ x,
                                                   bf16* __restrict__ xT,
                                                   bf16* __restrict__ xb)
{
    __shared__ float T[64][68];
    const int b = blockIdx.z;
    const int l0 = blockIdx.x * 64, d0 = blockIdx.y * 64;
    const int tid = threadIdx.x;
    const float* xsrc = x + ((size_t)b * LL + l0) * DD + d0;
    bf16* xbdst = xb + ((size_t)b * LL + l0) * DD + d0;
    #pragma unroll
    for (int it = 0; it < 4; ++it) {
        const int c = tid + it * 256;
        const int lr = c >> 4, cc = (c & 15) * 4;
        const float4 v = *(const float4*)(xsrc + (size_t)lr * DD + cc);
        T[lr][cc] = v.x; T[lr][cc + 1] = v.y; T[lr][cc + 2] = v.z; T[lr][cc + 3] = v.w;
        bf16x4 p = {(bf16)v.x, (bf16)v.y, (bf16)v.z, (bf16)v.w};
        *(bf16x4*)(xbdst + (size_t)lr * DD + cc) = p;
    }
    __syncthreads();
    const int dl = tid >> 2, ls = (tid & 3) * 16;
    bf16x8 p0, p1;
    #pragma unroll
    for (int j = 0; j < 8; ++j) p0[j] = (bf16)T[ls + j][dl];
    #pragma unroll
    for (int j = 0; j < 8; ++j) p1[j] = (bf16)T[ls + 8 + j][dl];
    bf16* o = xT + ((size_t)b * DD + d0 + dl) * LL + l0 + ls;
    *(bf16x8*)o = p0;
    *(bf16x8*)(o + 8) = p1;
}

// ---------------------------------------------------------------------------
// K1: wb[m, a] = bf16(tanh(sum_d xb[m,d] * W1b[a,d]))   M=B*L, N=DA, K=D
// 1D grid 2048, XCD-swizzled (chunk=256); w = m_idx*4 + n_idx so the 4
// blocks sharing an xb m-panel are adjacent -> same XCD L2.
// ---------------------------------------------------------------------------
__global__ __launch_bounds__(256) void k_gemm1(const bf16* __restrict__ xb,
                                               const bf16* __restrict__ W1b,
                                               bf16* __restrict__ wb)
{
    const int w = xcd_swz(blockIdx.x, 8);      // nwg=2048, chunk=256
    const int n0 = (w & 3) * 128;
    const size_t m0 = (size_t)(w >> 2) * 128;
    floatx4 acc[4][4];
    #pragma unroll
    for (int i = 0; i < 4; ++i)
        #pragma unroll
        for (int j = 0; j < 4; ++j) { floatx4 z = {0.f, 0.f, 0.f, 0.f}; acc[i][j] = z; }
    gemm_core(xb + m0 * DD, W1b + (size_t)n0 * DD, DD, DD, DD, acc);

    const int tid = threadIdx.x, lane = tid & 63, wv = tid >> 6;
    const int wr = wv >> 1, wc = wv & 1, lm = lane & 15, quad = lane >> 4;
    const size_t row0 = m0 + wr * 64 + quad * 4;
    const int col0 = n0 + wc * 64 + lm;
    #pragma unroll
    for (int i = 0; i < 4; ++i)
        #pragma unroll
        for (int j = 0; j < 4; ++j)
            #pragma unroll
            for (int r = 0; r < 4; ++r)
                wb[(row0 + i * 16 + r) * DA_ + col0 + j * 16] = (bf16)fast_tanh(acc[i][j][r]);
}

// ---------------------------------------------------------------------------
// K2: logitsb[b, n, l] = bf16(sum_a W2b[n,a] * wb[b*L+l, a])
// 1D grid 2048, XCD-swizzled; w = c_idx*4 + m_idx so the 4 blocks sharing a
// wb l-panel are adjacent.
// ---------------------------------------------------------------------------
__global__ __launch_bounds__(256) void k_gemm2(const bf16* __restrict__ wb,
                                               const bf16* __restrict__ W2b,
                                               bf16* __restrict__ logitsb)
{
    const int w = xcd_swz(blockIdx.x, 8);      // nwg=2048, chunk=256
    const int c0 = (w >> 2) * 128;   // global l index (never straddles a batch)
    const int m0 = (w & 3) * 128;    // over NL
    floatx4 acc[4][4];
    #pragma unroll
    for (int i = 0; i < 4; ++i)
        #pragma unroll
        for (int j = 0; j < 4; ++j) { floatx4 z = {0.f, 0.f, 0.f, 0.f}; acc[i][j] = z; }
    gemm_core(W2b + (size_t)m0 * DA_, wb + (size_t)c0 * DA_, DA_, DA_, DA_, acc);

    const int b = c0 >> 11, lloc = c0 & (LL - 1);
    const int tid = threadIdx.x, lane = tid & 63, wv = tid >> 6;
    const int wr = wv >> 1, wc = wv & 1, lm = lane & 15, quad = lane >> 4;
    bf16* base = logitsb + ((size_t)b * NL_ + m0 + wr * 64 + quad * 4) * LL
               + lloc + wc * 64 + lm;
    #pragma unroll
    for (int i = 0; i < 4; ++i)
        #pragma unroll
        for (int j = 0; j < 4; ++j)
            #pragma unroll
            for (int r = 0; r < 4; ++r)
                base[(size_t)(i * 16 + r) * LL + j * 16] = (bf16)acc[i][j][r];
}

// ---------------------------------------------------------------------------
// K3: softmax over contiguous L per (b,n): read bf16 logits,
//     write fp32 att (output) + bf16 attb (for gemm3)
// ---------------------------------------------------------------------------
__global__ __launch_bounds__(256) void k_softmax(const bf16* __restrict__ logitsb,
                                                 float* __restrict__ att,
                                                 bf16* __restrict__ attb)
{
    const int tid = threadIdx.x;
    const bf16* p = logitsb + (size_t)blockIdx.x * LL;
    float* po = att + (size_t)blockIdx.x * LL;
    bf16* pb = attb + (size_t)blockIdx.x * LL;

    const bf16x8 v = *(const bf16x8*)(p + tid * 8);
    float f[8];
    #pragma unroll
    for (int j = 0; j < 8; ++j) f[j] = (float)v[j];

    __shared__ float red[8];
    float m = f[0];
    #pragma unroll
    for (int j = 1; j < 8; ++j) m = fmaxf(m, f[j]);
    #pragma unroll
    for (int off = 32; off; off >>= 1) m = fmaxf(m, __shfl_down(m, off));
    if ((tid & 63) == 0) red[tid >> 6] = m;
    __syncthreads();
    m = fmaxf(fmaxf(red[0], red[1]), fmaxf(red[2], red[3]));

    float s = 0.f;
    #pragma unroll
    for (int j = 0; j < 8; ++j) { f[j] = __expf(f[j] - m); s += f[j]; }
    #pragma unroll
    for (int off = 32; off; off >>= 1) s += __shfl_down(s, off);
    if ((tid & 63) == 0) red[4 + (tid >> 6)] = s;
    __syncthreads();
    s = red[4] + red[5] + red[6] + red[7];

    const float inv = 1.0f / s;
    float4 o0, o1;
    o0.x = f[0] * inv; o0.y = f[1] * inv; o0.z = f[2] * inv; o0.w = f[3] * inv;
    o1.x = f[4] * inv; o1.y = f[5] * inv; o1.z = f[6] * inv; o1.w = f[7] * inv;
    *(float4*)(po + tid * 8) = o0;
    *(float4*)(po + tid * 8 + 4) = o1;
    bf16x8 q = {(bf16)o0.x, (bf16)o0.y, (bf16)o0.z, (bf16)o0.w,
                (bf16)o1.x, (bf16)o1.y, (bf16)o1.z, (bf16)o1.w};
    *(bf16x8*)(pb + tid * 8) = q;
}

// ---------------------------------------------------------------------------
// K4: ctx[b, n, d] = sum_l attb[b,n,l] * xT[b,d,l]
//     + fused wo partials: wo[b,n] += sum_{d in tile} ctx*W3 (atomicAdd fp32)
// 1D grid 512, XCD-swizzled (chunk=64): each XCD owns 4 whole batches ->
// attb[b]+xT[b] (4 MB) stays L2-resident, fetch ~= read-once.
// ---------------------------------------------------------------------------
__global__ __launch_bounds__(256) void k_gemm3(const bf16* __restrict__ attb,
                                               const bf16* __restrict__ xT,
                                               float* __restrict__ ctx,
                                               const float* __restrict__ W3,
                                               float* __restrict__ wo)
{
    const int w = xcd_swz(blockIdx.x, 6);      // nwg=512, chunk=64
    const int b  = w >> 4;
    const int m0 = ((w >> 2) & 3) * 128;   // over NL
    const int n0 = (w & 3) * 128;          // over D
    floatx4 acc[4][4];
    #pragma unroll
    for (int i = 0; i < 4; ++i)
        #pragma unroll
        for (int j = 0; j < 4; ++j) { floatx4 z = {0.f, 0.f, 0.f, 0.f}; acc[i][j] = z; }
    gemm_core(attb + ((size_t)b * NL_ + m0) * LL,
              xT + ((size_t)b * DD + n0) * LL, LL, LL, LL, acc);

    const int tid = threadIdx.x, lane = tid & 63, wv = tid >> 6;
    const int wr = wv >> 1, wc = wv & 1, lm = lane & 15, quad = lane >> 4;
    float* base = ctx + ((size_t)b * NL_ + m0 + wr * 64 + quad * 4) * DD
                + n0 + wc * 64 + lm;
    #pragma unroll
    for (int i = 0; i < 4; ++i)
        #pragma unroll
        for (int j = 0; j < 4; ++j)
            #pragma unroll
            for (int r = 0; r < 4; ++r)
                base[(size_t)(i * 16 + r) * DD + j * 16] = acc[i][j][r];

    // fused wo: this thread's acc covers n = m0+wr*64+quad*4+i*16+r,
    //                                  d = n0+wc*64+lm+j*16
    const int nbase = m0 + wr * 64 + quad * 4;
    const int dbase = n0 + wc * 64 + lm;
    #pragma unroll
    for (int i = 0; i < 4; ++i) {
        #pragma unroll
        for (int r = 0; r < 4; ++r) {
            const int n = nbase + i * 16 + r;
            float s = 0.f;
            #pragma unroll
            for (int j = 0; j < 4; ++j)
                s += acc[i][j][r] * W3[(size_t)n * DD + dbase + j * 16];
            // reduce across the 16 lm lanes of this quad (lm==0 keeps result)
            #pragma unroll
            for (int off = 8; off; off >>= 1) s += __shfl_down(s, off);
            if (lm == 0) atomicAdd(&wo[(size_t)b * NL_ + n], s);
        }
    }
}

// ---------------------------------------------------------------------------
extern "C" void kernel_launch(void* const* d_in, const int* in_sizes, int n_in,
                              void* d_out, int out_size, void* d_ws, size_t ws_size,
                              hipStream_t stream)
{
    const float* x  = (const float*)d_in[0];
    const float* W1 = (const float*)d_in[1];
    const float* W2 = (const float*)d_in[2];
    const float* W3 = (const float*)d_in[3];
    const float* b3 = (const float*)d_in[4];

    float* out = (float*)d_out;
    float* ctx = out;                               // [B, NL, D]
    float* wo  = out + (size_t)BB * NL_ * DD;       // [B, NL]
    float* att = wo + (size_t)BB * NL_;             // [B, NL, L]

    // ws layout (193 MB):
    //   R0 xT [B,D,L]          64 MB
    //   R1 xb [B*L,D] -> logitsb [B,NL,L]  64 MB (xb dead after gemm1)
    //   R2 wb [B*L,DA] -> attb [B,NL,L]    64 MB (wb dead after gemm2)
    //   R3 W1b, W2b            1 MB
    char* wsp = (char*)d_ws;
    const size_t M64 = (size_t)64 * 1024 * 1024;
    bf16* xT      = (bf16*)(wsp);
    bf16* xb      = (bf16*)(wsp + M64);
    bf16* logitsb = (bf16*)(wsp + M64);
    bf16* wb      = (bf16*)(wsp + 2 * M64);
    bf16* attb    = (bf16*)(wsp + 2 * M64);
    bf16* W1b     = (bf16*)(wsp + 3 * M64);
    bf16* W2b     = W1b + (size_t)DA_ * DD;

    k_cvt<<<(DA_ * DD) / 1024, 256, 0, stream>>>(W1, W1b, DA_ * DD);
    k_cvt<<<(NL_ * DA_) / 1024, 256, 0, stream>>>(W2, W2b, NL_ * DA_);
    k_init_wo<<<(BB * NL_) / 256, 256, 0, stream>>>(b3, wo);
    k_transpose<<<dim3(LL / 64, DD / 64, BB), 256, 0, stream>>>(x, xT, xb);
    k_gemm1<<<2048, 256, 0, stream>>>(xb, W1b, wb);
    k_gemm2<<<2048, 256, 0, stream>>>(wb, W2b, logitsb);
    k_softmax<<<BB * NL_, 256, 0, stream>>>(logitsb, att, attb);
    k_gemm3<<<512, 256, 0, stream>>>(attb, xT, ctx, W3, wo);
}